// Round 6
// baseline (671.001 us; speedup 1.0000x reference)
//
#include <hip/hip_runtime.h>
#include <math.h>

// LSTM B=8192,T=512,IN=3,H=32,OUT=2 fp32.
// R6: 8 batches/wave as TWO independent 4-batch groups (R5 layout each),
// software-interleaved in one instruction stream so the compiler fills each
// group's dependency-chain stalls (exp/rcp/shuffle tail) with the other
// group's MFMAs. 1024 waves = 1/SIMD (256 blocks x 256 thr). Shared A-frags.
// x-preacts added post-MFMA (C=0) -> no C-operand cndmasks in the chain.
// Batches replicated across 4 column-quadrants; replicas split the 8 units
// 4-ways -> 2 units/lane/group. Zero LDS, zero barriers.
// Weights pre-scaled by -log2e (-2log2e for g) -> raw v_exp_f32.

namespace {
constexpr int   kT   = 512;
constexpr float kL2E = 1.44269504088896340736f;
}

typedef __bf16 bf16x8 __attribute__((ext_vector_type(8)));
typedef float  f32x4  __attribute__((ext_vector_type(4)));

union Frag {
    bf16x8 v;
    unsigned short u[8];
    unsigned int   d[4];
};

__device__ __forceinline__ unsigned short bf_rne(float f) {
    unsigned u = __float_as_uint(f);
    u += 0x7fffu + ((u >> 16) & 1u);
    return (unsigned short)(u >> 16);
}
__device__ __forceinline__ float bf_tof(unsigned short h) {
    return __uint_as_float((unsigned)h << 16);
}
__device__ __forceinline__ float fast_exp2(float v) { return __builtin_amdgcn_exp2f(v); }
__device__ __forceinline__ float fast_rcp(float v)  { return __builtin_amdgcn_rcpf(v); }
__device__ __forceinline__ unsigned pck(unsigned short a, unsigned short b) {
    return (unsigned)a | ((unsigned)b << 16);
}

#define MFMA16 __builtin_amdgcn_mfma_f32_16x16x32_bf16

extern "C" __global__ __launch_bounds__(256, 1)
void lstm_duo(const float* __restrict__ x,
              const float* __restrict__ W_ih,
              const float* __restrict__ W_hh,
              const float* __restrict__ b_ih,
              const float* __restrict__ b_hh,
              const float* __restrict__ W_fc,
              const float* __restrict__ b_fc,
              float* __restrict__ out) {
    const int lane = threadIdx.x & 63;
    const int wv   = threadIdx.x >> 6;          // wave in block, 0..3
    const int gw   = blockIdx.x * 4 + wv;       // global wave id, 0..1023
    const int n    = lane & 15;                 // B/D column
    const int q    = lane >> 4;                 // quad
    const int bat  = n & 3;                     // batch within group
    const int rh   = (n >> 2) & 1;              // reg-pair selector
    const int p    = (n >> 3) & 1;              // chunk-parity selector
    const bool prh = (rh != 0);
    const bool pp1 = (p != 0);

    // ---- shared A-frags: permuted scaled W_hh (hi/lo) ----
    // chunk cc (g=cc>>1, pc=cc&1): A row m holds W row
    // R = 32g + 8(m>>2) + 4pc + (m&3) => D row 4q+r = gate g, unit 8q+4pc+r.
    Frag Ah[8], Al[8];
#pragma unroll
    for (int cc = 0; cc < 8; ++cc) {
        const int   g  = cc >> 1, pc = cc & 1;
        const float s  = (g == 2) ? -2.0f * kL2E : -kL2E;
        const int   R  = 32 * g + 8 * (n >> 2) + 4 * pc + (n & 3);
#pragma unroll
        for (int j = 0; j < 8; ++j) {
            const float w = W_hh[R * 32 + 8 * q + j] * s;
            const unsigned short hb = bf_rne(w);
            Ah[cc].u[j] = hb;
            Al[cc].u[j] = bf_rne(w - bf_tof(hb));
        }
    }

    // ---- shared per-lane x-path constants (my units u0, u0+1) ----
    const int u0 = 8 * q + 4 * p + 2 * rh;
    float xw[4][2][3], xbias[4][2];
#pragma unroll
    for (int g = 0; g < 4; ++g) {
        const float s = (g == 2) ? -2.0f * kL2E : -kL2E;
#pragma unroll
        for (int j2 = 0; j2 < 2; ++j2) {
            const int R = 32 * g + u0 + j2;
#pragma unroll
            for (int k = 0; k < 3; ++k) xw[g][j2][k] = W_ih[R * 3 + k] * s;
            xbias[g][j2] = (b_ih[R] + b_hh[R]) * s;
        }
    }

    // ---- per-group state ----
    const float* xb[2];
    float cst[2][2], hfull[2][2], xc[2][3];
    Frag Bh[2], Bl[2];
#pragma unroll
    for (int gi = 0; gi < 2; ++gi) {
        const int b = gw * 8 + gi * 4 + bat;
        xb[gi] = x + (size_t)b * kT * 3;
        cst[gi][0] = cst[gi][1] = 0.f;
        hfull[gi][0] = hfull[gi][1] = 0.f;
#pragma unroll
        for (int j = 0; j < 4; ++j) { Bh[gi].d[j] = 0; Bl[gi].d[j] = 0; }
        xc[gi][0] = xb[gi][0]; xc[gi][1] = xb[gi][1]; xc[gi][2] = xb[gi][2];
    }

    for (int t = 0; t < kT; ++t) {
        // ---- MFMAs for both groups (independent chains; compiler interleaves) ----
        f32x4 acc[2][8];
        const f32x4 z = {0.f, 0.f, 0.f, 0.f};
#pragma unroll
        for (int gi = 0; gi < 2; ++gi) {
#pragma unroll
            for (int cc = 0; cc < 8; ++cc) acc[gi][cc] = MFMA16(Ah[cc].v, Bh[gi].v, z, 0, 0, 0);
#pragma unroll
            for (int cc = 0; cc < 8; ++cc) acc[gi][cc] = MFMA16(Al[cc].v, Bh[gi].v, acc[gi][cc], 0, 0, 0);
#pragma unroll
            for (int cc = 0; cc < 8; ++cc) acc[gi][cc] = MFMA16(Ah[cc].v, Bl[gi].v, acc[gi][cc], 0, 0, 0);
        }

        const int tn = (t + 1 < kT) ? t + 1 : t;

#pragma unroll
        for (int gi = 0; gi < 2; ++gi) {
            // exact fp32 x-preacts for my 8 consumed slots (off the MFMA path)
            float xp[4][2];
#pragma unroll
            for (int g = 0; g < 4; ++g)
#pragma unroll
                for (int j2 = 0; j2 < 2; ++j2)
                    xp[g][j2] = fmaf(xc[gi][0], xw[g][j2][0],
                                fmaf(xc[gi][1], xw[g][j2][1],
                                fmaf(xc[gi][2], xw[g][j2][2], xbias[g][j2])));

            // prefetch next x
            const float xn0 = xb[gi][tn * 3 + 0];
            const float xn1 = xb[gi][tn * 3 + 1];
            const float xn2 = xb[gi][tn * 3 + 2];

            // select my 8 preacts + add x-part
            float P[4][2];
#pragma unroll
            for (int g = 0; g < 4; ++g) {
#pragma unroll
                for (int j2 = 0; j2 < 2; ++j2) {
                    const float ve = prh ? acc[gi][2 * g + 0][2 + j2] : acc[gi][2 * g + 0][j2];
                    const float vo = prh ? acc[gi][2 * g + 1][2 + j2] : acc[gi][2 * g + 1][j2];
                    P[g][j2] = (pp1 ? vo : ve) + xp[g][j2];
                }
            }

            // c/h update for my 2 units
            unsigned short hh[2], hl[2];
#pragma unroll
            for (int j2 = 0; j2 < 2; ++j2) {
                const float Ei = fast_exp2(P[0][j2]);
                const float Ef = fast_exp2(P[1][j2]);
                float       Eg = fast_exp2(P[2][j2]);
                const float Eo = fast_exp2(P[3][j2]);
                Eg = fminf(Eg, 1e30f);
                const float sf  = fast_rcp(1.0f + Ef);
                const float dig = fast_rcp((1.0f + Ei) * (1.0f + Eg));
                const float ig  = (1.0f - Eg) * dig;
                const float c   = fmaf(sf, cst[gi][j2], ig);
                cst[gi][j2] = c;
                float Ec = fast_exp2(c * (-2.0f * kL2E));
                Ec = fminf(Ec, 1e30f);
                const float doc = fast_rcp((1.0f + Eo) * (1.0f + Ec));
                const float h   = (1.0f - Ec) * doc;
                hfull[gi][j2] = h;
                hh[j2] = bf_rne(h);
                hl[j2] = bf_rne(h - bf_tof(hh[j2]));
            }

            // assemble next B-frags across the replica quad
            const unsigned myhi = pck(hh[0], hh[1]);
            const unsigned mylo = pck(hl[0], hl[1]);
            const unsigned othi = __shfl_xor(myhi, 4, 64);
            const unsigned otlo = __shfl_xor(mylo, 4, 64);
            const unsigned eA = prh ? othi : myhi;
            const unsigned eB = prh ? myhi : othi;
            const unsigned eC = prh ? otlo : mylo;
            const unsigned eD = prh ? mylo : otlo;
            const unsigned fA = __shfl_xor(eA, 8, 64);
            const unsigned fB = __shfl_xor(eB, 8, 64);
            const unsigned fC = __shfl_xor(eC, 8, 64);
            const unsigned fD = __shfl_xor(eD, 8, 64);
            Bh[gi].d[0] = pp1 ? fA : eA;
            Bh[gi].d[1] = pp1 ? fB : eB;
            Bh[gi].d[2] = pp1 ? eA : fA;
            Bh[gi].d[3] = pp1 ? eB : fB;
            Bl[gi].d[0] = pp1 ? fC : eC;
            Bl[gi].d[1] = pp1 ? fD : eD;
            Bl[gi].d[2] = pp1 ? eC : fC;
            Bl[gi].d[3] = pp1 ? eD : fD;

            xc[gi][0] = xn0; xc[gi][1] = xn1; xc[gi][2] = xn2;
        }
    }

    // ---- epilogue per group ----
#pragma unroll
    for (int gi = 0; gi < 2; ++gi) {
        float s0 = 0.f, s1 = 0.f;
#pragma unroll
        for (int j2 = 0; j2 < 2; ++j2) {
            const int u = u0 + j2;
            s0 = fmaf(hfull[gi][j2], W_fc[u], s0);
            s1 = fmaf(hfull[gi][j2], W_fc[32 + u], s1);
        }
        s0 += __shfl_xor(s0, 4, 64);  s1 += __shfl_xor(s1, 4, 64);
        s0 += __shfl_xor(s0, 8, 64);  s1 += __shfl_xor(s1, 8, 64);
        s0 += __shfl_xor(s0, 16, 64); s1 += __shfl_xor(s1, 16, 64);
        s0 += __shfl_xor(s0, 32, 64); s1 += __shfl_xor(s1, 32, 64);
        if (lane < 4) {
            const int b = gw * 8 + gi * 4 + bat;
            out[(size_t)b * 2 + 0] = s0 + b_fc[0];
            out[(size_t)b * 2 + 1] = s1 + b_fc[1];
        }
    }
}

extern "C" void kernel_launch(void* const* d_in, const int* in_sizes, int n_in,
                              void* d_out, int out_size, void* d_ws, size_t ws_size,
                              hipStream_t stream) {
    const float* x    = (const float*)d_in[0];
    const float* W_ih = (const float*)d_in[1];
    const float* W_hh = (const float*)d_in[2];
    const float* b_ih = (const float*)d_in[3];
    const float* b_hh = (const float*)d_in[4];
    const float* W_fc = (const float*)d_in[5];
    const float* b_fc = (const float*)d_in[6];
    float* out = (float*)d_out;

    const int batch = in_sizes[0] / (kT * 3);   // 8192
    dim3 grid(batch / 32);                      // 256 blocks (1 per CU)
    dim3 block(256);                            // 4 waves -> 1 per SIMD
    hipLaunchKernelGGL(lstm_duo, grid, block, 0, stream,
                       x, W_ih, W_hh, b_ih, b_hh, W_fc, b_fc, out);
}